// Round 12
// baseline (3539.796 us; speedup 1.0000x reference)
//
#include <hip/hip_runtime.h>
#include <math.h>

#define S_ANCH 1024
#define B_QRY  2048
#define N_TOT  3072
#define D_DIM  1352
#define D_PAD  1408   // padded D: u16/psi stride, GEMM2 K, c16T rows
#define F_NUM  10
#define N_TV   19
#define NPART  44     // 22 n-tiles * 2 wave-halves in GEMM1

static const size_t SD    = (size_t)S_ANCH * D_DIM;
static const size_t NS    = (size_t)N_TOT * S_ANCH;
static const size_t CST   = (size_t)D_PAD * S_ANCH;   // one c16T plane
static const size_t PSIP  = (size_t)N_TOT * D_PAD;    // one psi plane
static const size_t OUT_Z = (size_t)B_QRY * F_NUM * S_ANCH;

typedef __attribute__((ext_vector_type(8))) short bf16x8;
typedef __attribute__((ext_vector_type(4))) float f32x4;

struct W190 { float w[N_TV][F_NUM]; };

__device__ inline unsigned short f2bf(float x) {
    unsigned int u = __builtin_bit_cast(unsigned int, x);
    unsigned int r = (u + 0x7FFFu + ((u >> 16) & 1u)) >> 16;
    return (unsigned short)r;
}
__device__ inline float bf2f(unsigned short v) {
    unsigned int u = ((unsigned int)v) << 16;
    return __builtin_bit_cast(float, u);
}

__device__ __forceinline__ void stage16(const unsigned short* gp, unsigned short* lp) {
    __builtin_amdgcn_global_load_lds(
        (const __attribute__((address_space(1))) unsigned int*)(const void*)gp,
        (__attribute__((address_space(3))) unsigned int*)(void*)lp, 16, 0, 0);
}

// ------- init: zero z, z16, cost, rowsqP, psi-plane0 pad, t=0 out slice -------
__global__ __launch_bounds__(256) void init_kernel(float* __restrict__ z,
                                                   unsigned short* __restrict__ z16,
                                                   float* __restrict__ cost,
                                                   float* __restrict__ rowsqP,
                                                   unsigned short* __restrict__ psi0,
                                                   float* __restrict__ out) {
    size_t idx = (size_t)blockIdx.x * blockDim.x + threadIdx.x;
    size_t stride = (size_t)gridDim.x * blockDim.x;
    for (size_t i = idx; i < NS; i += stride) { z[i] = 0.f; z16[i] = 0; }
    const size_t NO = (size_t)B_QRY * S_ANCH;
    for (size_t i = idx; i < NO; i += stride) {
        size_t b = i >> 10, s = i & 1023;
        out[b * (size_t)(F_NUM * S_ANCH) + s] = 0.f;
    }
    const size_t NR = (size_t)NPART * N_TOT;
    for (size_t i = idx; i < NR; i += stride) rowsqP[i] = 0.f;
    const size_t NPAD = (size_t)N_TOT * (D_PAD - D_DIM);
    for (size_t i = idx; i < NPAD; i += stride) {
        size_t n = i / (D_PAD - D_DIM), c = i % (D_PAD - D_DIM);
        psi0[n * D_PAD + D_DIM + c] = 0;
    }
    if (idx == 0) cost[0] = 0.f;
}

// ---------------- ALL c_t planes in one pass over c_s ----------------
__global__ __launch_bounds__(256) void c_all_kernel(const float* __restrict__ cs,
                                                    unsigned short* __restrict__ cT,
                                                    float* __restrict__ cfp, W190 W) {
    __shared__ float tile[32][65];
    int d0 = blockIdx.x * 64, s0 = blockIdx.y * 32;
    int t = threadIdx.x;
    int d_l = t & 63, s_base = t >> 6;
    int d = d0 + d_l;
    bool dok = (d < D_DIM);
    float creg[8][F_NUM];
#pragma unroll
    for (int it = 0; it < 8; it++) {
        int s = s0 + s_base + it * 4;
        const float* p = cs + ((size_t)s * D_DIM + d) * F_NUM;
#pragma unroll
        for (int f = 0; f < F_NUM; f++) creg[it][f] = dok ? p[f] : 0.f;
    }
    for (int j = 0; j < N_TV; j++) {
        float v[8];
#pragma unroll
        for (int it = 0; it < 8; it++) {
            float s = 0.f;
#pragma unroll
            for (int f = 0; f < F_NUM; f++) s += creg[it][f] * W.w[j][f];
            v[it] = s;
            tile[s_base + it * 4][d_l] = s;
        }
        if ((j & 1) == 0 && j >= 2 && dok) {
            int gi = (j >> 1) - 1;
#pragma unroll
            for (int it = 0; it < 8; it++)
                cfp[(size_t)gi * SD + (size_t)(s0 + s_base + it * 4) * D_DIM + d] = v[it];
        }
        __syncthreads();
        int s_l = t & 31, dr = t >> 5;
#pragma unroll
        for (int p8 = 0; p8 < 8; p8++) {
            int dd = dr + p8 * 8;
            cT[(size_t)j * CST + (size_t)(d0 + dd) * S_ANCH + s0 + s_l] = f2bf(tile[s_l][dd]);
        }
        __syncthreads();
    }
}

// ---------------- ALL psi_t planes: conv once, 19 freq-dots ----------------
__global__ __launch_bounds__(256) void conv_psi_all_kernel(const float* __restrict__ data,
                                                           const float* __restrict__ inputs,
                                                           const float* __restrict__ cw,
                                                           const float* __restrict__ cb,
                                                           unsigned short* __restrict__ psi_all,
                                                           W190 W) {
    __shared__ float wsh[720];
    __shared__ float bsh[80];
    for (int i = threadIdx.x; i < 720; i += 256) wsh[i] = cw[i];
    for (int i = threadIdx.x; i < 80; i += 256) bsh[i] = cb[i];
    __syncthreads();
    size_t idx = (size_t)blockIdx.x * 256 + threadIdx.x;
    if (idx >= (size_t)N_TOT * 8 * 169) return;
    int pos = (int)(idx % 169);
    int rest = (int)(idx / 169);
    int c8 = rest & 7;
    int n = rest >> 3;
    int oi = pos / 13, oj = pos % 13;
    const float* x = (n < S_ANCH) ? (data + (size_t)n * 784)
                                  : (inputs + (size_t)(n - S_ANCH) * 784);
    float vin[9];
#pragma unroll
    for (int kh = 0; kh < 3; kh++)
#pragma unroll
        for (int kw = 0; kw < 3; kw++)
            vin[kh * 3 + kw] = x[(2 * oi + kh) * 28 + (2 * oj + kw)];
    float s[F_NUM];
#pragma unroll
    for (int f = 0; f < F_NUM; f++) {
        int co = f * 8 + c8;
        float acc = bsh[co];
#pragma unroll
        for (int t = 0; t < 9; t++) acc += vin[t] * wsh[co * 9 + t];
        s[f] = acc;
    }
    size_t base = (size_t)n * D_PAD + c8 * 169 + pos;
#pragma unroll
    for (int j = 0; j < N_TV; j++) {
        float p = 0.f;
#pragma unroll
        for (int f = 0; f < F_NUM; f++) p += s[f] * W.w[j][f];
        psi_all[(size_t)j * PSIP + base] = f2bf(p);
    }
}

// ------- rowsq of psi plane 0 (for the t=0 shortcut: u == psi) -------
__global__ __launch_bounds__(256) void rowsq_psi_kernel(const unsigned short* __restrict__ psi0,
                                                        float* __restrict__ rowsqP) {
    int wv = threadIdx.x >> 6, lane = threadIdx.x & 63;
    int r = blockIdx.x * 4 + wv;
    const unsigned short* row = psi0 + (size_t)r * D_PAD;
    float s = 0.f;
    for (int c = lane; c < D_PAD / 8; c += 64) {
        int4 v = *(const int4*)(row + c * 8);
        const unsigned short* u = (const unsigned short*)&v;
#pragma unroll
        for (int e = 0; e < 8; e++) { float f = bf2f(u[e]); s += f * f; }
    }
    s += __shfl_xor(s, 1); s += __shfl_xor(s, 2); s += __shfl_xor(s, 4);
    s += __shfl_xor(s, 8); s += __shfl_xor(s, 16); s += __shfl_xor(s, 32);
    if (lane == 0) rowsqP[r] = s;   // slot 0; slots 1..43 zeroed by init
}

// ---- MFMA GEMM (NT), 64x64 tile, BK=32, 6-buf depth-5 counted-vmcnt ----
// NT loads/stores on all pure-streaming traffic (kill RFO + L2 pollution).
struct GemmArgs {
    const unsigned short* A; const unsigned short* B;
    int lda, ldb, K, gx;
    // MODE 0
    const unsigned short* psi16; unsigned short* u16; float* rowsqP;
    int do_cost;
    // MODE 0 (cost fusion) + MODE 2
    const float* cfp; float* cost;
    // MODE 1
    float* zcur; unsigned short* accb16; unsigned short* zt16; float* outp;
    int first, finish, tout; float alpha, h6;
};

template<int MODE>
__global__ __launch_bounds__(256) void mfma_gemm(GemmArgs g) {
    __shared__ __align__(16) unsigned short As[6][64][32];
    __shared__ __align__(16) unsigned short Bs[6][64][32];
    __shared__ float sclM[64], ahM[64], sclN[64], ahN[64];
    __shared__ float red4[4];
    const int nb = gridDim.x;
    const int lin = blockIdx.x;
    const int swz = (lin & 7) * (nb >> 3) + (lin >> 3);
    const int bx = swz % g.gx, by = swz / g.gx;
    const int bm = by * 64, bn = bx * 64;
    const int t = threadIdx.x;
    const int lane = t & 63, wv = t >> 6;
    const int wm = (wv >> 1) * 32, wn = (wv & 1) * 32;
    const int lr = lane & 15, lg = lane >> 4;
    const int srow = lane >> 2;
    const int gch = (lane & 3) ^ ((lane >> 3) & 3);
    const int sl = lg ^ ((lr >> 1) & 3);

    if (MODE == 1) {
        if (t < 128) {
            int r = (t < 64) ? (bm + t) : (bn + (t - 64));
            float tot = 0.f;
#pragma unroll
            for (int c = 0; c < NPART; c++) tot += g.rowsqP[(size_t)c * N_TOT + r];
            float norm = sqrtf(tot + 1e-6f);
            float sg = 1.f / (1.f + __expf(-norm));
            float sc = sg / norm;
            float a = 0.5f * tot * sc * sc;
            if (t < 64) { sclM[t] = sc; ahM[t] = a; }
            else        { sclN[t - 64] = sc; ahN[t - 64] = a; }
        }
    }

    f32x4 acc[2][2];
#pragma unroll
    for (int i = 0; i < 2; i++)
#pragma unroll
        for (int j = 0; j < 2; j++) acc[i][j] = (f32x4){0.f, 0.f, 0.f, 0.f};

    const unsigned short* Abase = g.A + (size_t)(bm + wv * 16 + srow) * g.lda + gch * 8;
    const unsigned short* Bbase = g.B + (size_t)(bn + wv * 16 + srow) * g.ldb + gch * 8;

    auto STAGE = [&](int k) {
        int buf = k % 6;
        stage16(Abase + (k << 5), &As[buf][wv * 16][0]);
        stage16(Bbase + (k << 5), &Bs[buf][wv * 16][0]);
    };
    auto COMPUTE = [&](int k) {
        int buf = k % 6;
        bf16x8 af[2], bf[2];
#pragma unroll
        for (int i = 0; i < 2; i++)
            af[i] = *(const bf16x8*)&As[buf][wm + i * 16 + lr][sl * 8];
#pragma unroll
        for (int j = 0; j < 2; j++)
            bf[j] = *(const bf16x8*)&Bs[buf][wn + j * 16 + lr][sl * 8];
#pragma unroll
        for (int i = 0; i < 2; i++)
#pragma unroll
            for (int j = 0; j < 2; j++)
                acc[i][j] = __builtin_amdgcn_mfma_f32_16x16x32_bf16(af[i], bf[j], acc[i][j], 0, 0, 0);
    };

    const int nt = g.K >> 5;   // 32 or 44; always > 6
    STAGE(0); STAGE(1); STAGE(2); STAGE(3); STAGE(4);
    for (int k = 0; k < nt - 5; ++k) {
        asm volatile("s_waitcnt vmcnt(8)" ::: "memory");
        __builtin_amdgcn_s_barrier();
        __builtin_amdgcn_sched_barrier(0);
        STAGE(k + 5);
        COMPUTE(k);
    }
    asm volatile("s_waitcnt vmcnt(8)" ::: "memory");
    __builtin_amdgcn_s_barrier(); __builtin_amdgcn_sched_barrier(0);
    COMPUTE(nt - 5);
    asm volatile("s_waitcnt vmcnt(6)" ::: "memory");
    __builtin_amdgcn_s_barrier(); __builtin_amdgcn_sched_barrier(0);
    COMPUTE(nt - 4);
    asm volatile("s_waitcnt vmcnt(4)" ::: "memory");
    __builtin_amdgcn_s_barrier(); __builtin_amdgcn_sched_barrier(0);
    COMPUTE(nt - 3);
    asm volatile("s_waitcnt vmcnt(2)" ::: "memory");
    __builtin_amdgcn_s_barrier(); __builtin_amdgcn_sched_barrier(0);
    COMPUTE(nt - 2);
    asm volatile("s_waitcnt vmcnt(0)" ::: "memory");
    __builtin_amdgcn_s_barrier(); __builtin_amdgcn_sched_barrier(0);
    COMPUTE(nt - 1);

    // ---------------- epilogues ----------------
    if (MODE == 0) {
        const bool docost = g.do_cost && (bm < S_ANCH);
        float cst = 0.f;
#pragma unroll
        for (int i = 0; i < 2; i++) {
#pragma unroll
            for (int reg = 0; reg < 4; reg++) {
                int m = bm + wm + i * 16 + lg * 4 + reg;
                float sq = 0.f;
#pragma unroll
                for (int j = 0; j < 2; j++) {
                    int n = bn + wn + j * 16 + lr;
                    float v = acc[i][j][reg];
                    bool nok = n < D_DIM;
                    if (docost && nok)
                        cst += v * __builtin_nontemporal_load(&g.cfp[(size_t)m * D_DIM + n]);
                    if (nok) v += bf2f(__builtin_nontemporal_load(&g.psi16[(size_t)m * D_PAD + n]));
                    else v = 0.f;
                    __builtin_nontemporal_store(f2bf(v), &g.u16[(size_t)m * D_PAD + n]);
                    sq += v * v;
                }
                sq += __shfl_xor(sq, 1);
                sq += __shfl_xor(sq, 2);
                sq += __shfl_xor(sq, 4);
                sq += __shfl_xor(sq, 8);
                if (lr == 0)
                    g.rowsqP[(size_t)(bx * 2 + (wn >> 5)) * N_TOT + m] = sq;
            }
        }
        if (docost) {
            cst += __shfl_xor(cst, 1); cst += __shfl_xor(cst, 2);
            cst += __shfl_xor(cst, 4); cst += __shfl_xor(cst, 8);
            cst += __shfl_xor(cst, 16); cst += __shfl_xor(cst, 32);
            if (lane == 0) red4[wv] = cst;
            __syncthreads();
            if (t == 0) atomicAdd(g.cost, red4[0] + red4[1] + red4[2] + red4[3]);
        }
    } else if (MODE == 1) {
        __syncthreads();  // stats visibility
#pragma unroll
        for (int i = 0; i < 2; i++) {
#pragma unroll
            for (int reg = 0; reg < 4; reg++) {
                int mi = wm + i * 16 + lg * 4 + reg;
                int m = bm + mi;
                float sm = sclM[mi], am = ahM[mi];
#pragma unroll
                for (int j = 0; j < 2; j++) {
                    int ni = wn + j * 16 + lr;
                    int n = bn + ni;
                    float uv = acc[i][j][reg] * sm * sclN[ni];
                    float kv = __expf(uv - am - ahN[ni]) * uv;
                    size_t idx = (size_t)m * S_ANCH + n;
                    if (!g.finish) {
                        float ab = g.first ? kv
                                 : (bf2f(__builtin_nontemporal_load(&g.accb16[idx])) + 2.0f * kv);
                        __builtin_nontemporal_store(f2bf(ab), &g.accb16[idx]);
                        float zt = __builtin_nontemporal_load(&g.zcur[idx]) + g.alpha * kv;
                        __builtin_nontemporal_store(f2bf(zt), &g.zt16[idx]);
                    } else {
                        float z = __builtin_nontemporal_load(&g.zcur[idx])
                                + g.h6 * (bf2f(__builtin_nontemporal_load(&g.accb16[idx])) + kv);
                        __builtin_nontemporal_store(z, &g.zcur[idx]);
                        __builtin_nontemporal_store(f2bf(z), &g.zt16[idx]);
                        if (m >= S_ANCH)
                            __builtin_nontemporal_store(z,
                                &g.outp[(size_t)(m - S_ANCH) * (F_NUM * S_ANCH)
                                        + (size_t)g.tout * S_ANCH + n]);
                    }
                }
            }
        }
    } else {
        float s = 0.f;
#pragma unroll
        for (int i = 0; i < 2; i++)
#pragma unroll
            for (int reg = 0; reg < 4; reg++) {
                int m = bm + wm + i * 16 + lg * 4 + reg;
#pragma unroll
                for (int j = 0; j < 2; j++) {
                    int n = bn + wn + j * 16 + lr;
                    if (n < D_DIM)
                        s += acc[i][j][reg] * __builtin_nontemporal_load(&g.cfp[(size_t)m * D_DIM + n]);
                }
            }
        s += __shfl_xor(s, 1); s += __shfl_xor(s, 2); s += __shfl_xor(s, 4);
        s += __shfl_xor(s, 8); s += __shfl_xor(s, 16); s += __shfl_xor(s, 32);
        if (lane == 0) red4[wv] = s;
        __syncthreads();
        if (t == 0) atomicAdd(g.cost, red4[0] + red4[1] + red4[2] + red4[3]);
    }
}

// ---------------- final: add conv_w/b square norm ----------------
__global__ __launch_bounds__(256) void final_kernel(const float* __restrict__ cw,
                                                    const float* __restrict__ cb,
                                                    const float* __restrict__ cost,
                                                    float* __restrict__ out) {
    float s = 0.f;
    for (int i = threadIdx.x; i < 720; i += 256) s += cw[i] * cw[i];
    for (int i = threadIdx.x; i < 80; i += 256) s += cb[i] * cb[i];
    for (int o = 32; o > 0; o >>= 1) s += __shfl_down(s, o);
    __shared__ float red[4];
    if ((threadIdx.x & 63) == 0) red[threadIdx.x >> 6] = s;
    __syncthreads();
    if (threadIdx.x == 0) out[0] = red[0] + red[1] + red[2] + red[3] + cost[0] / 10.0f;
}

// ---------------- host ----------------
extern "C" void kernel_launch(void* const* d_in, const int* in_sizes, int n_in,
                              void* d_out, int out_size, void* d_ws, size_t ws_size,
                              hipStream_t stream) {
    (void)in_sizes; (void)n_in; (void)out_size; (void)ws_size;
    const float* data   = (const float*)d_in[0];
    const float* inputs = (const float*)d_in[1];
    const float* conv_w = (const float*)d_in[2];
    const float* conv_b = (const float*)d_in[3];
    const float* c_s    = (const float*)d_in[4];
    float* out = (float*)d_out;

    char* ws = (char*)d_ws;
    size_t off = 0;
    auto alloc = [&](size_t bytes) {
        char* p = ws + off; off += (bytes + 255) & ~(size_t)255; return p;
    };
    unsigned short* c16T_all = (unsigned short*)alloc((size_t)N_TV * CST * 2);   // 54.8 MB
    float*          cfp_all  = (float*)alloc((size_t)9 * SD * 4);                // 49.8 MB
    unsigned short* psi_all  = (unsigned short*)alloc((size_t)N_TV * PSIP * 2);  // 164.4 MB
    unsigned short* u16      = (unsigned short*)alloc(PSIP * 2);
    float*          z_cur    = (float*)alloc(NS * 4);
    unsigned short* z16      = (unsigned short*)alloc(NS * 2);
    unsigned short* zt16     = (unsigned short*)alloc(NS * 2);
    unsigned short* accb16   = (unsigned short*)alloc(NS * 2);
    float*          rowsqP   = (float*)alloc((size_t)NPART * N_TOT * 4);
    float*          cost     = (float*)alloc(64);

    const double TAU_D = 6.2831853071795864769;
    float ts[F_NUM];
    for (int i = 0; i < F_NUM; i++) ts[i] = (float)((double)i / 9.0);
    W190 Wall;
    for (int j = 0; j < N_TV; j++) {
        float tt;
        if ((j & 1) == 0) tt = ts[j >> 1];
        else {
            int i = j >> 1;
            float h = ts[i + 1] - ts[i];
            tt = ts[i] + 0.5f * h;
        }
        for (int f = 0; f < F_NUM; f++) {
            float coeff = (float)(TAU_D * f);
            float targ = tt * coeff;
            Wall.w[j][f] = (float)cos((double)targ);
        }
    }

    init_kernel<<<2048, 256, 0, stream>>>(z_cur, z16, cost, rowsqP, psi_all, out);
    c_all_kernel<<<dim3(22, 32), 256, 0, stream>>>(c_s, c16T_all, cfp_all, Wall);
    const int conv_blocks = (int)(((size_t)N_TOT * 8 * 169 + 255) / 256);
    conv_psi_all_kernel<<<conv_blocks, 256, 0, stream>>>(data, inputs, conv_w, conv_b,
                                                         psi_all, Wall);

    GemmArgs g0 = {}; // GEMM1: u = z@cT + psi (+ fused cost at e=0)
    g0.lda = S_ANCH; g0.ldb = S_ANCH; g0.K = S_ANCH; g0.gx = 22;
    g0.u16 = u16; g0.rowsqP = rowsqP; g0.cost = cost;
    GemmArgs g1 = {}; // GEMM2: kernel + RK4 bookkeeping
    g1.lda = D_PAD; g1.ldb = D_PAD; g1.K = D_PAD; g1.gx = 16;
    g1.zcur = z_cur; g1.accb16 = accb16; g1.rowsqP = rowsqP;
    GemmArgs g2 = {}; // final cost quadratic form (t_9)
    g2.A = z16; g2.B = c16T_all + (size_t)18 * CST;
    g2.lda = S_ANCH; g2.ldb = S_ANCH; g2.K = S_ANCH; g2.gx = 22;
    g2.cfp = cfp_all + (size_t)8 * SD; g2.cost = cost;

    for (int i = 0; i < 9; i++) {
        float h = ts[i + 1] - ts[i];
        int js[4] = {2 * i, 2 * i + 1, 2 * i + 1, 2 * i + 2};
        float alphas[3] = {0.5f * h, 0.5f * h, h};
        for (int e = 0; e < 4; e++) {
            int j = js[e];
            const bool shortcut = (i == 0 && e == 0);   // z == 0 -> u == psi
            if (shortcut) {
                rowsq_psi_kernel<<<N_TOT / 4, 256, 0, stream>>>(psi_all, rowsqP);
            } else {
                g0.A = (e == 0) ? z16 : zt16;
                g0.B = c16T_all + (size_t)j * CST;
                g0.psi16 = psi_all + (size_t)j * PSIP;
                g0.do_cost = (e == 0 && i >= 1) ? 1 : 0;
                g0.cfp = (i >= 1) ? (cfp_all + (size_t)(i - 1) * SD) : cfp_all;
                mfma_gemm<0><<<22 * 48, 256, 0, stream>>>(g0);
            }
            g1.A = shortcut ? psi_all : u16;
            g1.B = shortcut ? psi_all : u16;
            g1.first = (e == 0); g1.finish = (e == 3);
            g1.alpha = (e < 3) ? alphas[e] : 0.f;
            g1.h6 = h / 6.0f; g1.tout = i + 1;
            g1.zt16 = (e < 3) ? zt16 : z16;
            g1.outp = out;
            mfma_gemm<1><<<16 * 48, 256, 0, stream>>>(g1);
        }
    }
    // cost contribution at t_9 (z16 holds z_{t9})
    mfma_gemm<2><<<22 * 16, 256, 0, stream>>>(g2);

    final_kernel<<<1, 256, 0, stream>>>(conv_w, conv_b, cost, out + OUT_Z);
}

// Round 13
// 2259.734 us; speedup vs baseline: 1.5665x; 1.5665x over previous
//
#include <hip/hip_runtime.h>
#include <math.h>

#define S_ANCH 1024
#define B_QRY  2048
#define N_TOT  3072
#define D_DIM  1352
#define D_PAD  1408   // padded D: u16/psi stride, GEMM2 K, c16T rows
#define F_NUM  10
#define N_TV   19
#define NPART  44     // 22 n-tiles * 2 wave-halves in GEMM1

static const size_t SD    = (size_t)S_ANCH * D_DIM;
static const size_t NS    = (size_t)N_TOT * S_ANCH;
static const size_t CST   = (size_t)D_PAD * S_ANCH;   // one c16T plane
static const size_t PSIP  = (size_t)N_TOT * D_PAD;    // one psi plane
static const size_t OUT_Z = (size_t)B_QRY * F_NUM * S_ANCH;

typedef __attribute__((ext_vector_type(8))) short bf16x8;
typedef __attribute__((ext_vector_type(4))) float f32x4;

struct W190 { float w[N_TV][F_NUM]; };

__device__ inline unsigned short f2bf(float x) {
    unsigned int u = __builtin_bit_cast(unsigned int, x);
    unsigned int r = (u + 0x7FFFu + ((u >> 16) & 1u)) >> 16;
    return (unsigned short)r;
}
__device__ inline float bf2f(unsigned short v) {
    unsigned int u = ((unsigned int)v) << 16;
    return __builtin_bit_cast(float, u);
}

__device__ __forceinline__ void stage16(const unsigned short* gp, unsigned short* lp) {
    __builtin_amdgcn_global_load_lds(
        (const __attribute__((address_space(1))) unsigned int*)(const void*)gp,
        (__attribute__((address_space(3))) unsigned int*)(void*)lp, 16, 0, 0);
}

// ------- init: zero z, z16, cost, rowsqP, psi-plane0 pad, t=0 out slice -------
__global__ __launch_bounds__(256) void init_kernel(float* __restrict__ z,
                                                   unsigned short* __restrict__ z16,
                                                   float* __restrict__ cost,
                                                   float* __restrict__ rowsqP,
                                                   unsigned short* __restrict__ psi0,
                                                   float* __restrict__ out) {
    size_t idx = (size_t)blockIdx.x * blockDim.x + threadIdx.x;
    size_t stride = (size_t)gridDim.x * blockDim.x;
    for (size_t i = idx; i < NS; i += stride) { z[i] = 0.f; z16[i] = 0; }
    const size_t NO = (size_t)B_QRY * S_ANCH;
    for (size_t i = idx; i < NO; i += stride) {
        size_t b = i >> 10, s = i & 1023;
        out[b * (size_t)(F_NUM * S_ANCH) + s] = 0.f;
    }
    const size_t NR = (size_t)NPART * N_TOT;
    for (size_t i = idx; i < NR; i += stride) rowsqP[i] = 0.f;
    const size_t NPAD = (size_t)N_TOT * (D_PAD - D_DIM);
    for (size_t i = idx; i < NPAD; i += stride) {
        size_t n = i / (D_PAD - D_DIM), c = i % (D_PAD - D_DIM);
        psi0[n * D_PAD + D_DIM + c] = 0;
    }
    if (idx == 0) cost[0] = 0.f;
}

// ---------------- ALL c_t planes in one pass over c_s ----------------
__global__ __launch_bounds__(256) void c_all_kernel(const float* __restrict__ cs,
                                                    unsigned short* __restrict__ cT,
                                                    float* __restrict__ cfp, W190 W) {
    __shared__ float tile[32][65];
    int d0 = blockIdx.x * 64, s0 = blockIdx.y * 32;
    int t = threadIdx.x;
    int d_l = t & 63, s_base = t >> 6;
    int d = d0 + d_l;
    bool dok = (d < D_DIM);
    float creg[8][F_NUM];
#pragma unroll
    for (int it = 0; it < 8; it++) {
        int s = s0 + s_base + it * 4;
        const float* p = cs + ((size_t)s * D_DIM + d) * F_NUM;
#pragma unroll
        for (int f = 0; f < F_NUM; f++) creg[it][f] = dok ? p[f] : 0.f;
    }
    for (int j = 0; j < N_TV; j++) {
        float v[8];
#pragma unroll
        for (int it = 0; it < 8; it++) {
            float s = 0.f;
#pragma unroll
            for (int f = 0; f < F_NUM; f++) s += creg[it][f] * W.w[j][f];
            v[it] = s;
            tile[s_base + it * 4][d_l] = s;
        }
        if ((j & 1) == 0 && j >= 2 && dok) {
            int gi = (j >> 1) - 1;
#pragma unroll
            for (int it = 0; it < 8; it++)
                cfp[(size_t)gi * SD + (size_t)(s0 + s_base + it * 4) * D_DIM + d] = v[it];
        }
        __syncthreads();
        int s_l = t & 31, dr = t >> 5;
#pragma unroll
        for (int p8 = 0; p8 < 8; p8++) {
            int dd = dr + p8 * 8;
            cT[(size_t)j * CST + (size_t)(d0 + dd) * S_ANCH + s0 + s_l] = f2bf(tile[s_l][dd]);
        }
        __syncthreads();
    }
}

// ---------------- ALL psi_t planes: conv once, 19 freq-dots ----------------
__global__ __launch_bounds__(256) void conv_psi_all_kernel(const float* __restrict__ data,
                                                           const float* __restrict__ inputs,
                                                           const float* __restrict__ cw,
                                                           const float* __restrict__ cb,
                                                           unsigned short* __restrict__ psi_all,
                                                           W190 W) {
    __shared__ float wsh[720];
    __shared__ float bsh[80];
    for (int i = threadIdx.x; i < 720; i += 256) wsh[i] = cw[i];
    for (int i = threadIdx.x; i < 80; i += 256) bsh[i] = cb[i];
    __syncthreads();
    size_t idx = (size_t)blockIdx.x * 256 + threadIdx.x;
    if (idx >= (size_t)N_TOT * 8 * 169) return;
    int pos = (int)(idx % 169);
    int rest = (int)(idx / 169);
    int c8 = rest & 7;
    int n = rest >> 3;
    int oi = pos / 13, oj = pos % 13;
    const float* x = (n < S_ANCH) ? (data + (size_t)n * 784)
                                  : (inputs + (size_t)(n - S_ANCH) * 784);
    float vin[9];
#pragma unroll
    for (int kh = 0; kh < 3; kh++)
#pragma unroll
        for (int kw = 0; kw < 3; kw++)
            vin[kh * 3 + kw] = x[(2 * oi + kh) * 28 + (2 * oj + kw)];
    float s[F_NUM];
#pragma unroll
    for (int f = 0; f < F_NUM; f++) {
        int co = f * 8 + c8;
        float acc = bsh[co];
#pragma unroll
        for (int t = 0; t < 9; t++) acc += vin[t] * wsh[co * 9 + t];
        s[f] = acc;
    }
    size_t base = (size_t)n * D_PAD + c8 * 169 + pos;
#pragma unroll
    for (int j = 0; j < N_TV; j++) {
        float p = 0.f;
#pragma unroll
        for (int f = 0; f < F_NUM; f++) p += s[f] * W.w[j][f];
        psi_all[(size_t)j * PSIP + base] = f2bf(p);
    }
}

// ------- rowsq of psi plane 0 (for the t=0 shortcut: u == psi) -------
__global__ __launch_bounds__(256) void rowsq_psi_kernel(const unsigned short* __restrict__ psi0,
                                                        float* __restrict__ rowsqP) {
    int wv = threadIdx.x >> 6, lane = threadIdx.x & 63;
    int r = blockIdx.x * 4 + wv;
    const unsigned short* row = psi0 + (size_t)r * D_PAD;
    float s = 0.f;
    for (int c = lane; c < D_PAD / 8; c += 64) {
        int4 v = *(const int4*)(row + c * 8);
        const unsigned short* u = (const unsigned short*)&v;
#pragma unroll
        for (int e = 0; e < 8; e++) { float f = bf2f(u[e]); s += f * f; }
    }
    s += __shfl_xor(s, 1); s += __shfl_xor(s, 2); s += __shfl_xor(s, 4);
    s += __shfl_xor(s, 8); s += __shfl_xor(s, 16); s += __shfl_xor(s, 32);
    if (lane == 0) rowsqP[r] = s;   // slot 0; slots 1..43 zeroed by init
}

// ---- MFMA GEMM (NT), 64x64 tile, BK=32, 6-buf depth-5 counted-vmcnt ----
// Epilogue inputs prefetched into registers BEFORE the K-loop (T14 async-split):
// their HBM latency hides under the MFMA pipeline instead of trailing it.
struct GemmArgs {
    const unsigned short* A; const unsigned short* B;
    int lda, ldb, K, gx;
    // MODE 0
    const unsigned short* psi16; unsigned short* u16; float* rowsqP;
    int do_cost;
    // MODE 0 (cost fusion) + MODE 2
    const float* cfp; float* cost;
    // MODE 1
    float* zcur; unsigned short* accb16; unsigned short* zt16; float* outp;
    int first, finish, tout; float alpha, h6;
};

template<int MODE>
__global__ __launch_bounds__(256) void mfma_gemm(GemmArgs g) {
    __shared__ __align__(16) unsigned short As[6][64][32];
    __shared__ __align__(16) unsigned short Bs[6][64][32];
    __shared__ float sclM[64], ahM[64], sclN[64], ahN[64];
    __shared__ float red4[4];
    const int nb = gridDim.x;
    const int lin = blockIdx.x;
    const int swz = (lin & 7) * (nb >> 3) + (lin >> 3);
    const int bx = swz % g.gx, by = swz / g.gx;
    const int bm = by * 64, bn = bx * 64;
    const int t = threadIdx.x;
    const int lane = t & 63, wv = t >> 6;
    const int wm = (wv >> 1) * 32, wn = (wv & 1) * 32;
    const int lr = lane & 15, lg = lane >> 4;
    const int srow = lane >> 2;
    const int gch = (lane & 3) ^ ((lane >> 3) & 3);
    const int sl = lg ^ ((lr >> 1) & 3);

    if (MODE == 1) {
        if (t < 128) {
            int r = (t < 64) ? (bm + t) : (bn + (t - 64));
            float tot = 0.f;
#pragma unroll
            for (int c = 0; c < NPART; c++) tot += g.rowsqP[(size_t)c * N_TOT + r];
            float norm = sqrtf(tot + 1e-6f);
            float sg = 1.f / (1.f + __expf(-norm));
            float sc = sg / norm;
            float a = 0.5f * tot * sc * sc;
            if (t < 64) { sclM[t] = sc; ahM[t] = a; }
            else        { sclN[t - 64] = sc; ahN[t - 64] = a; }
        }
    }

    // ---- T14: early epilogue-input loads (independent of MFMA results) ----
    const bool docost = (MODE == 0) && g.do_cost && (bm < S_ANCH);
    unsigned short psi_r[2][4][2];
    float cfp_r[2][4][2];
    float zc_r[2][4][2];
    unsigned short ab_r[2][4][2];
    if (MODE == 0) {
#pragma unroll
        for (int i = 0; i < 2; i++)
#pragma unroll
            for (int reg = 0; reg < 4; reg++) {
                int m = bm + wm + i * 16 + lg * 4 + reg;
#pragma unroll
                for (int j = 0; j < 2; j++) {
                    int n = bn + wn + j * 16 + lr;
                    psi_r[i][reg][j] = g.psi16[(size_t)m * D_PAD + n];
                    if (docost)
                        cfp_r[i][reg][j] = (n < D_DIM) ? g.cfp[(size_t)m * D_DIM + n] : 0.f;
                }
            }
    } else if (MODE == 1) {
#pragma unroll
        for (int i = 0; i < 2; i++)
#pragma unroll
            for (int reg = 0; reg < 4; reg++) {
                int m = bm + wm + i * 16 + lg * 4 + reg;
#pragma unroll
                for (int j = 0; j < 2; j++) {
                    int n = bn + wn + j * 16 + lr;
                    size_t idx = (size_t)m * S_ANCH + n;
                    zc_r[i][reg][j] = g.zcur[idx];
                    ab_r[i][reg][j] = g.accb16[idx];
                }
            }
    }
    __builtin_amdgcn_sched_barrier(0);   // pin early loads before staging

    f32x4 acc[2][2];
#pragma unroll
    for (int i = 0; i < 2; i++)
#pragma unroll
        for (int j = 0; j < 2; j++) acc[i][j] = (f32x4){0.f, 0.f, 0.f, 0.f};

    const unsigned short* Abase = g.A + (size_t)(bm + wv * 16 + srow) * g.lda + gch * 8;
    const unsigned short* Bbase = g.B + (size_t)(bn + wv * 16 + srow) * g.ldb + gch * 8;

    auto STAGE = [&](int k) {
        int buf = k % 6;
        stage16(Abase + (k << 5), &As[buf][wv * 16][0]);
        stage16(Bbase + (k << 5), &Bs[buf][wv * 16][0]);
    };
    auto COMPUTE = [&](int k) {
        int buf = k % 6;
        bf16x8 af[2], bf[2];
#pragma unroll
        for (int i = 0; i < 2; i++)
            af[i] = *(const bf16x8*)&As[buf][wm + i * 16 + lr][sl * 8];
#pragma unroll
        for (int j = 0; j < 2; j++)
            bf[j] = *(const bf16x8*)&Bs[buf][wn + j * 16 + lr][sl * 8];
#pragma unroll
        for (int i = 0; i < 2; i++)
#pragma unroll
            for (int j = 0; j < 2; j++)
                acc[i][j] = __builtin_amdgcn_mfma_f32_16x16x32_bf16(af[i], bf[j], acc[i][j], 0, 0, 0);
    };

    const int nt = g.K >> 5;   // 32 or 44; always > 6
    STAGE(0); STAGE(1); STAGE(2); STAGE(3); STAGE(4);
    for (int k = 0; k < nt - 5; ++k) {
        asm volatile("s_waitcnt vmcnt(8)" ::: "memory");
        __builtin_amdgcn_s_barrier();
        __builtin_amdgcn_sched_barrier(0);
        STAGE(k + 5);
        COMPUTE(k);
    }
    asm volatile("s_waitcnt vmcnt(8)" ::: "memory");
    __builtin_amdgcn_s_barrier(); __builtin_amdgcn_sched_barrier(0);
    COMPUTE(nt - 5);
    asm volatile("s_waitcnt vmcnt(6)" ::: "memory");
    __builtin_amdgcn_s_barrier(); __builtin_amdgcn_sched_barrier(0);
    COMPUTE(nt - 4);
    asm volatile("s_waitcnt vmcnt(4)" ::: "memory");
    __builtin_amdgcn_s_barrier(); __builtin_amdgcn_sched_barrier(0);
    COMPUTE(nt - 3);
    asm volatile("s_waitcnt vmcnt(2)" ::: "memory");
    __builtin_amdgcn_s_barrier(); __builtin_amdgcn_sched_barrier(0);
    COMPUTE(nt - 2);
    asm volatile("s_waitcnt vmcnt(0)" ::: "memory");
    __builtin_amdgcn_s_barrier(); __builtin_amdgcn_sched_barrier(0);
    COMPUTE(nt - 1);

    // ---------------- epilogues (inputs already in registers) ----------------
    if (MODE == 0) {
        float cst = 0.f;
#pragma unroll
        for (int i = 0; i < 2; i++) {
#pragma unroll
            for (int reg = 0; reg < 4; reg++) {
                int m = bm + wm + i * 16 + lg * 4 + reg;
                float sq = 0.f;
#pragma unroll
                for (int j = 0; j < 2; j++) {
                    int n = bn + wn + j * 16 + lr;
                    float v = acc[i][j][reg];
                    bool nok = n < D_DIM;
                    if (docost) cst += v * cfp_r[i][reg][j];
                    if (nok) v += bf2f(psi_r[i][reg][j]);
                    else v = 0.f;
                    g.u16[(size_t)m * D_PAD + n] = f2bf(v);
                    sq += v * v;
                }
                sq += __shfl_xor(sq, 1);
                sq += __shfl_xor(sq, 2);
                sq += __shfl_xor(sq, 4);
                sq += __shfl_xor(sq, 8);
                if (lr == 0)
                    g.rowsqP[(size_t)(bx * 2 + (wn >> 5)) * N_TOT + m] = sq;
            }
        }
        if (docost) {
            cst += __shfl_xor(cst, 1); cst += __shfl_xor(cst, 2);
            cst += __shfl_xor(cst, 4); cst += __shfl_xor(cst, 8);
            cst += __shfl_xor(cst, 16); cst += __shfl_xor(cst, 32);
            if (lane == 0) red4[wv] = cst;
            __syncthreads();
            if (t == 0) atomicAdd(g.cost, red4[0] + red4[1] + red4[2] + red4[3]);
        }
    } else if (MODE == 1) {
        __syncthreads();  // stats visibility
#pragma unroll
        for (int i = 0; i < 2; i++) {
#pragma unroll
            for (int reg = 0; reg < 4; reg++) {
                int mi = wm + i * 16 + lg * 4 + reg;
                int m = bm + mi;
                float sm = sclM[mi], am = ahM[mi];
#pragma unroll
                for (int j = 0; j < 2; j++) {
                    int ni = wn + j * 16 + lr;
                    int n = bn + ni;
                    float uv = acc[i][j][reg] * sm * sclN[ni];
                    float kv = __expf(uv - am - ahN[ni]) * uv;
                    size_t idx = (size_t)m * S_ANCH + n;
                    if (!g.finish) {
                        float ab = g.first ? kv : (bf2f(ab_r[i][reg][j]) + 2.0f * kv);
                        g.accb16[idx] = f2bf(ab);
                        float zt = zc_r[i][reg][j] + g.alpha * kv;
                        g.zt16[idx] = f2bf(zt);
                    } else {
                        float z = zc_r[i][reg][j] + g.h6 * (bf2f(ab_r[i][reg][j]) + kv);
                        g.zcur[idx] = z;
                        g.zt16[idx] = f2bf(z);
                        if (m >= S_ANCH)
                            g.outp[(size_t)(m - S_ANCH) * (F_NUM * S_ANCH)
                                   + (size_t)g.tout * S_ANCH + n] = z;
                    }
                }
            }
        }
    } else {
        float s = 0.f;
#pragma unroll
        for (int i = 0; i < 2; i++)
#pragma unroll
            for (int reg = 0; reg < 4; reg++) {
                int m = bm + wm + i * 16 + lg * 4 + reg;
#pragma unroll
                for (int j = 0; j < 2; j++) {
                    int n = bn + wn + j * 16 + lr;
                    if (n < D_DIM) s += acc[i][j][reg] * g.cfp[(size_t)m * D_DIM + n];
                }
            }
        s += __shfl_xor(s, 1); s += __shfl_xor(s, 2); s += __shfl_xor(s, 4);
        s += __shfl_xor(s, 8); s += __shfl_xor(s, 16); s += __shfl_xor(s, 32);
        if (lane == 0) red4[wv] = s;
        __syncthreads();
        if (t == 0) atomicAdd(g.cost, red4[0] + red4[1] + red4[2] + red4[3]);
    }
}

// ---------------- final: add conv_w/b square norm ----------------
__global__ __launch_bounds__(256) void final_kernel(const float* __restrict__ cw,
                                                    const float* __restrict__ cb,
                                                    const float* __restrict__ cost,
                                                    float* __restrict__ out) {
    float s = 0.f;
    for (int i = threadIdx.x; i < 720; i += 256) s += cw[i] * cw[i];
    for (int i = threadIdx.x; i < 80; i += 256) s += cb[i] * cb[i];
    for (int o = 32; o > 0; o >>= 1) s += __shfl_down(s, o);
    __shared__ float red[4];
    if ((threadIdx.x & 63) == 0) red[threadIdx.x >> 6] = s;
    __syncthreads();
    if (threadIdx.x == 0) out[0] = red[0] + red[1] + red[2] + red[3] + cost[0] / 10.0f;
}

// ---------------- host ----------------
extern "C" void kernel_launch(void* const* d_in, const int* in_sizes, int n_in,
                              void* d_out, int out_size, void* d_ws, size_t ws_size,
                              hipStream_t stream) {
    (void)in_sizes; (void)n_in; (void)out_size; (void)ws_size;
    const float* data   = (const float*)d_in[0];
    const float* inputs = (const float*)d_in[1];
    const float* conv_w = (const float*)d_in[2];
    const float* conv_b = (const float*)d_in[3];
    const float* c_s    = (const float*)d_in[4];
    float* out = (float*)d_out;

    char* ws = (char*)d_ws;
    size_t off = 0;
    auto alloc = [&](size_t bytes) {
        char* p = ws + off; off += (bytes + 255) & ~(size_t)255; return p;
    };
    unsigned short* c16T_all = (unsigned short*)alloc((size_t)N_TV * CST * 2);   // 54.8 MB
    float*          cfp_all  = (float*)alloc((size_t)9 * SD * 4);                // 49.8 MB
    unsigned short* psi_all  = (unsigned short*)alloc((size_t)N_TV * PSIP * 2);  // 164.4 MB
    unsigned short* u16      = (unsigned short*)alloc(PSIP * 2);
    float*          z_cur    = (float*)alloc(NS * 4);
    unsigned short* z16      = (unsigned short*)alloc(NS * 2);
    unsigned short* zt16     = (unsigned short*)alloc(NS * 2);
    unsigned short* accb16   = (unsigned short*)alloc(NS * 2);
    float*          rowsqP   = (float*)alloc((size_t)NPART * N_TOT * 4);
    float*          cost     = (float*)alloc(64);

    const double TAU_D = 6.2831853071795864769;
    float ts[F_NUM];
    for (int i = 0; i < F_NUM; i++) ts[i] = (float)((double)i / 9.0);
    W190 Wall;
    for (int j = 0; j < N_TV; j++) {
        float tt;
        if ((j & 1) == 0) tt = ts[j >> 1];
        else {
            int i = j >> 1;
            float h = ts[i + 1] - ts[i];
            tt = ts[i] + 0.5f * h;
        }
        for (int f = 0; f < F_NUM; f++) {
            float coeff = (float)(TAU_D * f);
            float targ = tt * coeff;
            Wall.w[j][f] = (float)cos((double)targ);
        }
    }

    init_kernel<<<2048, 256, 0, stream>>>(z_cur, z16, cost, rowsqP, psi_all, out);
    c_all_kernel<<<dim3(22, 32), 256, 0, stream>>>(c_s, c16T_all, cfp_all, Wall);
    const int conv_blocks = (int)(((size_t)N_TOT * 8 * 169 + 255) / 256);
    conv_psi_all_kernel<<<conv_blocks, 256, 0, stream>>>(data, inputs, conv_w, conv_b,
                                                         psi_all, Wall);

    GemmArgs g0 = {}; // GEMM1: u = z@cT + psi (+ fused cost at e=0)
    g0.lda = S_ANCH; g0.ldb = S_ANCH; g0.K = S_ANCH; g0.gx = 22;
    g0.u16 = u16; g0.rowsqP = rowsqP; g0.cost = cost;
    GemmArgs g1 = {}; // GEMM2: kernel + RK4 bookkeeping
    g1.lda = D_PAD; g1.ldb = D_PAD; g1.K = D_PAD; g1.gx = 16;
    g1.zcur = z_cur; g1.accb16 = accb16; g1.rowsqP = rowsqP;
    GemmArgs g2 = {}; // final cost quadratic form (t_9)
    g2.A = z16; g2.B = c16T_all + (size_t)18 * CST;
    g2.lda = S_ANCH; g2.ldb = S_ANCH; g2.K = S_ANCH; g2.gx = 22;
    g2.cfp = cfp_all + (size_t)8 * SD; g2.cost = cost;

    for (int i = 0; i < 9; i++) {
        float h = ts[i + 1] - ts[i];
        int js[4] = {2 * i, 2 * i + 1, 2 * i + 1, 2 * i + 2};
        float alphas[3] = {0.5f * h, 0.5f * h, h};
        for (int e = 0; e < 4; e++) {
            int j = js[e];
            const bool shortcut = (i == 0 && e == 0);   // z == 0 -> u == psi
            if (shortcut) {
                rowsq_psi_kernel<<<N_TOT / 4, 256, 0, stream>>>(psi_all, rowsqP);
            } else {
                g0.A = (e == 0) ? z16 : zt16;
                g0.B = c16T_all + (size_t)j * CST;
                g0.psi16 = psi_all + (size_t)j * PSIP;
                g0.do_cost = (e == 0 && i >= 1) ? 1 : 0;
                g0.cfp = (i >= 1) ? (cfp_all + (size_t)(i - 1) * SD) : cfp_all;
                mfma_gemm<0><<<22 * 48, 256, 0, stream>>>(g0);
            }
            g1.A = shortcut ? psi_all : u16;
            g1.B = shortcut ? psi_all : u16;
            g1.first = (e == 0); g1.finish = (e == 3);
            g1.alpha = (e < 3) ? alphas[e] : 0.f;
            g1.h6 = h / 6.0f; g1.tout = i + 1;
            g1.zt16 = (e < 3) ? zt16 : z16;
            g1.outp = out;
            mfma_gemm<1><<<16 * 48, 256, 0, stream>>>(g1);
        }
    }
    // cost contribution at t_9 (z16 holds z_{t9})
    mfma_gemm<2><<<22 * 16, 256, 0, stream>>>(g2);

    final_kernel<<<1, 256, 0, stream>>>(conv_w, conv_b, cost, out + OUT_Z);
}